// Round 1
// baseline (4245.140 us; speedup 1.0000x reference)
//
#include <hip/hip_runtime.h>

#define NCPS   180
#define VOXELS (96*96*96)
#define HB     560
#define WB     560
#define IMG    (HB*WB)

__global__ __launch_bounds__(256) void proj_kernel(
    const float* __restrict__ bev,
    const float* __restrict__ grid,
    float* __restrict__ out)
{
    int tid = blockIdx.x * blockDim.x + threadIdx.x;
    if (tid >= VOXELS) return;

    float acc0 = 0.f, acc1 = 0.f;
    const float2* gptr = (const float2*)grid + tid;

    for (int n = 0; n < NCPS; ++n) {
        float2 g = gptr[(size_t)n * VOXELS];
        // normalized [-1,1] -> pixel coords, align_corners=True
        float x = (g.x + 1.0f) * (0.5f * (float)(WB - 1));
        float y = (g.y + 1.0f) * (0.5f * (float)(HB - 1));

        // any-tap-valid window: (-1, WB) x (-1, HB); outside -> contributes 0
        if (x > -1.0f && x < (float)WB && y > -1.0f && y < (float)HB) {
            float x0f = floorf(x), y0f = floorf(y);
            int x0 = (int)x0f, y0 = (int)y0f;
            int x1 = x0 + 1,   y1 = y0 + 1;
            float wx1 = x - x0f, wy1 = y - y0f;
            float wx0 = 1.f - wx1, wy0 = 1.f - wy1;

            float vx0 = (x0 >= 0 && x0 < WB) ? 1.f : 0.f;
            float vx1 = (x1 >= 0 && x1 < WB) ? 1.f : 0.f;
            float vy0 = (y0 >= 0 && y0 < HB) ? 1.f : 0.f;
            float vy1 = (y1 >= 0 && y1 < HB) ? 1.f : 0.f;

            int x0c = min(max(x0, 0), WB - 1);
            int x1c = min(max(x1, 0), WB - 1);
            int y0c = min(max(y0, 0), HB - 1);
            int y1c = min(max(y1, 0), HB - 1);

            float w00 = wy0 * wx0 * vy0 * vx0;
            float w01 = wy0 * wx1 * vy0 * vx1;
            float w10 = wy1 * wx0 * vy1 * vx0;
            float w11 = wy1 * wx1 * vy1 * vx1;

            const float* p0 = bev + (size_t)n * (2 * IMG);
            const float* p1 = p0 + IMG;
            int i00 = y0c * WB + x0c;
            int i01 = y0c * WB + x1c;
            int i10 = y1c * WB + x0c;
            int i11 = y1c * WB + x1c;

            acc0 += w00 * p0[i00] + w01 * p0[i01] + w10 * p0[i10] + w11 * p0[i11];
            acc1 += w00 * p1[i00] + w01 * p1[i01] + w10 * p1[i10] + w11 * p1[i11];
        }
    }

    out[tid]          = acc0;
    out[VOXELS + tid] = acc1;
}

extern "C" void kernel_launch(void* const* d_in, const int* in_sizes, int n_in,
                              void* d_out, int out_size, void* d_ws, size_t ws_size,
                              hipStream_t stream) {
    const float* bev  = (const float*)d_in[0];  // (1,180,2,560,560) fp32
    const float* grid = (const float*)d_in[1];  // (180,96,96,96,2) fp32
    float* out        = (float*)d_out;          // (1,2,96,96,96) fp32

    int threads = 256;
    int blocks  = (VOXELS + threads - 1) / threads;  // 3456
    proj_kernel<<<blocks, threads, 0, stream>>>(bev, grid, out);
}